// Round 1
// baseline (2053.947 us; speedup 1.0000x reference)
//
#include <hip/hip_runtime.h>
#include <hip/hip_bf16.h>
#include <math.h>

typedef unsigned short u16;
typedef __bf16 bf16x8_t __attribute__((ext_vector_type(8)));
typedef float  f32x4_t  __attribute__((ext_vector_type(4)));
typedef float  f32x8_t  __attribute__((ext_vector_type(8)));
typedef u16    u16x4_t  __attribute__((ext_vector_type(4)));
typedef u16    u16x8_t  __attribute__((ext_vector_type(8)));

// ---------- helpers ----------
__device__ __forceinline__ u16 f2b(float f) {
  unsigned u = __builtin_bit_cast(unsigned, f);
  u += 0x7fffu + ((u >> 16) & 1u);      // RNE; inputs are finite
  return (u16)(u >> 16);
}
__device__ __forceinline__ float b2f(u16 h) {
  unsigned u = ((unsigned)h) << 16;
  return __builtin_bit_cast(float, u);
}
__device__ __forceinline__ float sigm_(float x) { return 1.0f / (1.0f + __expf(-x)); }
__device__ __forceinline__ float tanh_(float x) { return 1.0f - 2.0f / (__expf(2.0f * x) + 1.0f); }

__device__ __forceinline__ void gload16(const void* g, void* l) {
  __builtin_amdgcn_global_load_lds(
      (__attribute__((address_space(1))) void*)(g),
      (__attribute__((address_space(3))) void*)(l), 16, 0, 0);
}

// ---------- convert fp32 activations -> bf16 into concatenated A panel ----------
// dst[r*ldd + c0 + c] = bf16(src[r*C + c]); one thread = 4 elements
__global__ void cvt_act_kernel(const float* __restrict__ src, u16* __restrict__ dst,
                               int C, int ldd, int c0) {
  long i = (long)blockIdx.x * blockDim.x + threadIdx.x;
  long e = i * 4;
  int r = (int)(e / C);
  int c = (int)(e % C);
  f32x4_t v = *(const f32x4_t*)(src + e);
  u16x4_t o;
  o[0] = f2b(v[0]); o[1] = f2b(v[1]); o[2] = f2b(v[2]); o[3] = f2b(v[3]);
  *(u16x4_t*)(dst + (long)r * ldd + c0 + c) = o;
}

// ---------- transpose-convert weight: src [K,N] fp32 -> dst[(n0+n)*ldd + k0+k] bf16 ----------
__global__ void cvt_wt_kernel(const float* __restrict__ src, u16* __restrict__ dst,
                              int K, int N, int ldd, int n0, int k0) {
  __shared__ float tile[32][33];
  int kt = blockIdx.y * 32, nt = blockIdx.x * 32;
  int tx = threadIdx.x, ty = threadIdx.y;   // block (32,8)
#pragma unroll
  for (int i = 0; i < 32; i += 8)
    tile[ty + i][tx] = src[(long)(kt + ty + i) * N + nt + tx];
  __syncthreads();
#pragma unroll
  for (int i = 0; i < 32; i += 8)
    dst[(long)(n0 + nt + ty + i) * ldd + (k0 + kt + tx)] = f2b(tile[tx][ty + i]);
}

// ---------- bf16 GEMM, m97 structure: 128x128 tile, BK=64, 4 waves, 16x16x32 MFMA ----------
// MODE 0: A1[16384,5120] x W1t[8192,5120]^T-layout -> G1 bf16 [16384,8192], segmented K
// MODE 1: A2[16384,4096] x W2t[2048,4096]          -> G2 bf16 [16384,2048], segmented K
template <int MODE>
__global__ __launch_bounds__(256) void gemm_bf16_kernel(
    const u16* __restrict__ A, const u16* __restrict__ Bt, u16* __restrict__ Cout) {
  constexpr int BK = 64;
  constexpr int LDA = (MODE == 0) ? 5120 : 4096;
  constexpr int LDB = (MODE == 0) ? 5120 : 4096;
  constexpr int NCOL = (MODE == 0) ? 8192 : 2048;
  constexpr int NBN = NCOL / 128;

  __shared__ u16 As[128 * BK];
  __shared__ u16 Bs[128 * BK];

  // XCD-bijective swizzle (grid % 8 == 0 in both modes)
  int bid = blockIdx.x;
  int cpx = gridDim.x >> 3;
  bid = (bid & 7) * cpx + (bid >> 3);

  int mb = bid / NBN, nb = bid % NBN;
  int m0 = mb * 128, n0 = nb * 128;

  int kstart, kend;
  if (MODE == 0) { kstart = 0; kend = (nb < 32) ? 5120 : ((nb < 56) ? 3072 : 2048); }
  else           { kstart = (nb < 8) ? 0 : 2048; kend = kstart + 2048; }

  int tid = threadIdx.x;
  int lane = tid & 63;
  int wr = (tid >> 7) & 1;   // wave row (waves 0,1 | 2,3)
  int wc = (tid >> 6) & 1;   // wave col

  f32x4_t acc[4][4];
#pragma unroll
  for (int m = 0; m < 4; ++m)
#pragma unroll
    for (int n = 0; n < 4; ++n) acc[m][n] = (f32x4_t){0.f, 0.f, 0.f, 0.f};

  const long aBase = (long)m0 * LDA;
  const long bBase = (long)n0 * LDB;
  const int lr = lane & 15;

  for (int k0 = kstart; k0 < kend; k0 += BK) {
    // stage A tile [128][64] and B tile [128][64] (both row-major in k), 16B per lane-slot
#pragma unroll
    for (int q = 0; q < 4; ++q) {
      int s = q * 256 + tid;            // slot 0..1023
      int row = s >> 3;                 // 8 slots (64 bf16) per row
      int kk = (s & 7) * 8;
      gload16(A + aBase + (long)row * LDA + k0 + kk, &As[s * 8]);
    }
#pragma unroll
    for (int q = 0; q < 4; ++q) {
      int s = q * 256 + tid;
      int row = s >> 3;
      int kk = (s & 7) * 8;
      gload16(Bt + bBase + (long)row * LDB + k0 + kk, &Bs[s * 8]);
    }
    __syncthreads();   // compiler drains vmcnt before s_barrier

#pragma unroll
    for (int kc = 0; kc < 2; ++kc) {
      bf16x8_t av[4], bv[4];
      int kk = kc * 32 + (lane >> 4) * 8;
#pragma unroll
      for (int m = 0; m < 4; ++m)
        av[m] = *(const bf16x8_t*)&As[(wr * 64 + m * 16 + lr) * BK + kk];
#pragma unroll
      for (int n = 0; n < 4; ++n)
        bv[n] = *(const bf16x8_t*)&Bs[(wc * 64 + n * 16 + lr) * BK + kk];
#pragma unroll
      for (int m = 0; m < 4; ++m)
#pragma unroll
        for (int n = 0; n < 4; ++n)
          acc[m][n] = __builtin_amdgcn_mfma_f32_16x16x32_bf16(av[m], bv[n], acc[m][n], 0, 0, 0);
    }
    __syncthreads();   // protect LDS before next stage
  }

  // C/D layout: col = lane&15, row = (lane>>4)*4 + reg   [verified m89/m91]
  int lr4 = (lane >> 4) * 4;
#pragma unroll
  for (int m = 0; m < 4; ++m) {
    int rg = m0 + wr * 64 + m * 16 + lr4;
#pragma unroll
    for (int n = 0; n < 4; ++n) {
      int cg = n0 + wc * 64 + n * 16 + lr;
#pragma unroll
      for (int r = 0; r < 4; ++r)
        Cout[(long)(rg + r) * NCOL + cg] = f2b(acc[m][n][r]);
    }
  }
}

// ---------- pass2: gates -> c_new (fp32 out), A2 = [bf16(c_new) | bf16(tanh(c_new))] ----------
__global__ void pass2_kernel(const u16* __restrict__ G1, const float* __restrict__ c_t,
                             const float* __restrict__ bias_i, const float* __restrict__ bias_f,
                             const float* __restrict__ bias_c,
                             float* __restrict__ c_new_out, u16* __restrict__ A2) {
  long i = (long)blockIdx.x * blockDim.x + threadIdx.x;
  long e = i * 8;
  int b = (int)(e >> 11);
  int j = (int)(e & 2047);
  const u16* row = G1 + (long)b * 8192;
  u16x8_t ip = *(const u16x8_t*)(row + j);
  u16x8_t fp = *(const u16x8_t*)(row + 2048 + j);
  u16x8_t gp = *(const u16x8_t*)(row + 4096 + j);
  f32x8_t cp = *(const f32x8_t*)(c_t + (long)b * 2048 + j);
  f32x8_t bi = *(const f32x8_t*)(bias_i + j);
  f32x8_t bf = *(const f32x8_t*)(bias_f + j);
  f32x8_t bc = *(const f32x8_t*)(bias_c + j);

  f32x8_t cn;
  u16x8_t cb, rb;
#pragma unroll
  for (int r = 0; r < 8; ++r) {
    float ig = sigm_(b2f(ip[r]) + bi[r]);
    float fg = sigm_(b2f(fp[r]) + bf[r]);
    float g  = tanh_(b2f(gp[r]) + bc[r]);
    float c  = fg * cp[r] + ig * g;
    cn[r] = c;
    cb[r] = f2b(c);
    rb[r] = f2b(tanh_(c));
  }
  *(f32x8_t*)(c_new_out + (long)b * 2048 + j) = cn;
  u16* a2row = A2 + (long)b * 4096;
  *(u16x8_t*)(a2row + j) = cb;
  *(u16x8_t*)(a2row + 2048 + j) = rb;
}

// ---------- pass3: h_new = sigmoid(og_pre + c@Woc + bias_o) * (m_t + xr) ----------
__global__ void pass3_kernel(const u16* __restrict__ G1, const u16* __restrict__ G2,
                             const float* __restrict__ bias_o, float* __restrict__ h_out) {
  long i = (long)blockIdx.x * blockDim.x + threadIdx.x;
  long e = i * 8;
  int b = (int)(e >> 10);
  int j = (int)(e & 1023);
  const u16* row1 = G1 + (long)b * 8192;
  const u16* row2 = G2 + (long)b * 2048;
  u16x8_t ogp = *(const u16x8_t*)(row1 + 6144 + j);
  u16x8_t xrp = *(const u16x8_t*)(row1 + 7168 + j);
  u16x8_t ocg = *(const u16x8_t*)(row2 + j);
  u16x8_t mt  = *(const u16x8_t*)(row2 + 1024 + j);
  f32x8_t bo  = *(const f32x8_t*)(bias_o + j);
  f32x8_t h;
#pragma unroll
  for (int r = 0; r < 8; ++r) {
    float og = sigm_(b2f(ogp[r]) + b2f(ocg[r]) + bo[r]);
    h[r] = og * (b2f(mt[r]) + b2f(xrp[r]));
  }
  *(f32x8_t*)(h_out + (long)b * 1024 + j) = h;
}

// ---------- launch ----------
extern "C" void kernel_launch(void* const* d_in, const int* in_sizes, int n_in,
                              void* d_out, int out_size, void* d_ws, size_t ws_size,
                              hipStream_t stream) {
  const float* x_t      = (const float*)d_in[0];
  const float* h_t      = (const float*)d_in[1];
  const float* c_t      = (const float*)d_in[2];
  const float* w_if_x   = (const float*)d_in[3];
  const float* w_if_h   = (const float*)d_in[4];
  const float* w_if_c   = (const float*)d_in[5];
  const float* bias_i   = (const float*)d_in[6];
  const float* bias_f   = (const float*)d_in[7];
  const float* w_c_x    = (const float*)d_in[8];
  const float* w_c_h    = (const float*)d_in[9];
  const float* bias_c   = (const float*)d_in[10];
  const float* w_o_x    = (const float*)d_in[11];
  const float* w_o_h    = (const float*)d_in[12];
  const float* w_o_c    = (const float*)d_in[13];
  const float* bias_o   = (const float*)d_in[14];
  const float* w_r_proj = (const float*)d_in[15];
  const float* w_r_x    = (const float*)d_in[16];

  char* ws = (char*)d_ws;
  // layout (512 MiB total):
  //   A1  [16384,5120] bf16 @ 0          (160 MiB)
  //   W1t [8192,5120]  bf16 @ 160 MiB    ( 80 MiB)
  //   G1  [16384,8192] bf16 @ 240 MiB    (256 MiB)
  //   W2t [2048,4096]  bf16 @ 496 MiB    ( 16 MiB)
  // aliases (dead after GEMM1):
  //   A2  [16384,4096] bf16 @ 0          (128 MiB, inside A1)
  //   G2  [16384,2048] bf16 @ 160 MiB    ( 64 MiB, inside W1t)
  u16* A1  = (u16*)(ws);
  u16* W1t = (u16*)(ws + 167772160L);
  u16* G1  = (u16*)(ws + 251658240L);
  u16* W2t = (u16*)(ws + 520093696L);
  u16* A2  = (u16*)(ws);
  u16* G2  = (u16*)(ws + 167772160L);

  float* h_out = (float*)d_out;
  float* c_out = h_out + 16384L * 1024L;

  // --- stage 0: conversions ---
  cvt_act_kernel<<<32768, 256, 0, stream>>>(x_t, A1, 2048, 5120, 0);
  cvt_act_kernel<<<16384, 256, 0, stream>>>(h_t, A1, 1024, 5120, 2048);
  cvt_act_kernel<<<32768, 256, 0, stream>>>(c_t, A1, 2048, 5120, 3072);

  dim3 tb(32, 8);
  cvt_wt_kernel<<<dim3(4096 / 32, 2048 / 32), tb, 0, stream>>>(w_if_x,   W1t, 2048, 4096, 5120, 0,    0);
  cvt_wt_kernel<<<dim3(4096 / 32, 1024 / 32), tb, 0, stream>>>(w_if_h,   W1t, 1024, 4096, 5120, 0,    2048);
  cvt_wt_kernel<<<dim3(4096 / 32, 2048 / 32), tb, 0, stream>>>(w_if_c,   W1t, 2048, 4096, 5120, 0,    3072);
  cvt_wt_kernel<<<dim3(2048 / 32, 2048 / 32), tb, 0, stream>>>(w_c_x,    W1t, 2048, 2048, 5120, 4096, 0);
  cvt_wt_kernel<<<dim3(2048 / 32, 1024 / 32), tb, 0, stream>>>(w_c_h,    W1t, 1024, 2048, 5120, 4096, 2048);
  cvt_wt_kernel<<<dim3(1024 / 32, 2048 / 32), tb, 0, stream>>>(w_o_x,    W1t, 2048, 1024, 5120, 6144, 0);
  cvt_wt_kernel<<<dim3(1024 / 32, 1024 / 32), tb, 0, stream>>>(w_o_h,    W1t, 1024, 1024, 5120, 6144, 2048);
  cvt_wt_kernel<<<dim3(1024 / 32, 2048 / 32), tb, 0, stream>>>(w_r_x,    W1t, 2048, 1024, 5120, 7168, 0);
  cvt_wt_kernel<<<dim3(1024 / 32, 2048 / 32), tb, 0, stream>>>(w_o_c,    W2t, 2048, 1024, 4096, 0,    0);
  cvt_wt_kernel<<<dim3(1024 / 32, 2048 / 32), tb, 0, stream>>>(w_r_proj, W2t, 2048, 1024, 4096, 1024, 2048);

  // --- stage 1: big fused GEMM -> all pre-activations ---
  gemm_bf16_kernel<0><<<8192, 256, 0, stream>>>(A1, W1t, G1);

  // --- stage 2: elementwise gates -> c_new + A2 ---
  pass2_kernel<<<16384, 256, 0, stream>>>(G1, c_t, bias_i, bias_f, bias_c, c_out, A2);

  // --- stage 3: [c_new|r_t] GEMM -> og peephole + m_t ---
  gemm_bf16_kernel<1><<<2048, 256, 0, stream>>>(A2, W2t, G2);

  // --- stage 4: h_new ---
  pass3_kernel<<<8192, 256, 0, stream>>>(G1, G2, bias_o, h_out);
}

// Round 2
// 1862.933 us; speedup vs baseline: 1.1025x; 1.1025x over previous
//
#include <hip/hip_runtime.h>
#include <hip/hip_bf16.h>
#include <math.h>

typedef unsigned short u16;
typedef __bf16 bf16x8_t __attribute__((ext_vector_type(8)));
typedef float  f32x4_t  __attribute__((ext_vector_type(4)));
typedef float  f32x8_t  __attribute__((ext_vector_type(8)));
typedef u16    u16x4_t  __attribute__((ext_vector_type(4)));
typedef u16    u16x8_t  __attribute__((ext_vector_type(8)));

// ---------- helpers ----------
__device__ __forceinline__ u16 f2b(float f) {
  unsigned u = __builtin_bit_cast(unsigned, f);
  u += 0x7fffu + ((u >> 16) & 1u);      // RNE; inputs are finite
  return (u16)(u >> 16);
}
__device__ __forceinline__ float b2f(u16 h) {
  unsigned u = ((unsigned)h) << 16;
  return __builtin_bit_cast(float, u);
}
__device__ __forceinline__ float sigm_(float x) { return 1.0f / (1.0f + __expf(-x)); }
__device__ __forceinline__ float tanh_(float x) { return 1.0f - 2.0f / (__expf(2.0f * x) + 1.0f); }

__device__ __forceinline__ void gload16(const void* g, void* l) {
  __builtin_amdgcn_global_load_lds(
      (__attribute__((address_space(1))) void*)(g),
      (__attribute__((address_space(3))) void*)(l), 16, 0, 0);
}

// ---------- convert fp32 activations -> bf16 into concatenated A panel ----------
__global__ void cvt_act_kernel(const float* __restrict__ src, u16* __restrict__ dst,
                               int C, int ldd, int c0) {
  long i = (long)blockIdx.x * blockDim.x + threadIdx.x;
  long e = i * 4;
  int r = (int)(e / C);
  int c = (int)(e % C);
  f32x4_t v = *(const f32x4_t*)(src + e);
  u16x4_t o;
  o[0] = f2b(v[0]); o[1] = f2b(v[1]); o[2] = f2b(v[2]); o[3] = f2b(v[3]);
  *(u16x4_t*)(dst + (long)r * ldd + c0 + c) = o;
}

// ---------- transpose-convert weight: src [K,N] fp32 -> dst[(n0+n)*ldd + k0+k] bf16 ----------
__global__ void cvt_wt_kernel(const float* __restrict__ src, u16* __restrict__ dst,
                              int K, int N, int ldd, int n0, int k0) {
  __shared__ float tile[32][33];
  int kt = blockIdx.y * 32, nt = blockIdx.x * 32;
  int tx = threadIdx.x, ty = threadIdx.y;   // block (32,8)
#pragma unroll
  for (int i = 0; i < 32; i += 8)
    tile[ty + i][tx] = src[(long)(kt + ty + i) * N + nt + tx];
  __syncthreads();
#pragma unroll
  for (int i = 0; i < 32; i += 8)
    dst[(long)(n0 + nt + ty + i) * ldd + (k0 + kt + tx)] = f2b(tile[tx][ty + i]);
}

// ==========================================================================
// 256x256 deep-pipelined bf16 GEMM (T3+T4+T5), BK=32, 8 waves (2M x 4N).
// LDS: 3-slot ring x (A 16KB + B 16KB) = 96 KiB.
//   Tile layout (per operand): 4 k-slice planes of [256 rows] x 16B.
//   Fragment reads are 256B-contiguous per 16-lane group -> conflict-free.
// Pipeline: while computing tile t (slot t%3), stage tile t+2 (slot (t+2)%3).
//   Boundary s_waitcnt vmcnt(4) -> tile t+1 resident, tile t+2 in flight.
// MODE 0: A1[16384,5120] x W1t[8192,5120]^T-layout -> G1 bf16, segmented K
// MODE 1: A2[16384,4096] x W2t[2048,4096]          -> G2 bf16, segmented K
// ==========================================================================
template <int MODE>
__global__ __launch_bounds__(512, 2) void gemm256_kernel(
    const u16* __restrict__ A, const u16* __restrict__ Bt, u16* __restrict__ Cout) {
  constexpr int LDA  = (MODE == 0) ? 5120 : 4096;   // == LDB in both modes
  constexpr int NCOL = (MODE == 0) ? 8192 : 2048;
  constexpr int NBN  = NCOL / 256;
  constexpr int SLOT = 16384;   // u16 per ring slot (A 8192 + B 8192)

  __shared__ u16 lds[3 * SLOT];  // 96 KiB

  // XCD-bijective swizzle (grid % 8 == 0 in both modes)
  int bid = blockIdx.x;
  int cpx = gridDim.x >> 3;
  bid = (bid & 7) * cpx + (bid >> 3);

  int mb = bid / NBN, nb = bid % NBN;
  int m0 = mb * 256, n0 = nb * 256;

  int kstart, kend;
  if (MODE == 0) { kstart = 0; kend = (nb < 16) ? 5120 : ((nb < 28) ? 3072 : 2048); }
  else           { kstart = (nb < 4) ? 0 : 2048; kend = kstart + 2048; }
  const int NT = (kend - kstart) >> 5;   // K-tiles of 32; always >= 64 here

  const int tid  = threadIdx.x;
  const int lane = tid & 63;
  const int wid  = tid >> 6;       // 0..7
  const int wr   = wid >> 2;       // 0..1  (wave row: 128 output rows)
  const int wc   = wid & 3;        // 0..3  (wave col: 64 output cols)

  // ---- staging addressing (per-thread) ----
  // seg0 = wid, seg1 = wid+8; plane kk = seg&3, rowblk = seg>>2.
  // LDS dest offset (u16): (seg&3)*2048 + (seg>>2)*512 + lane*8 ; seg1 = seg0 + 1024.
  const int doff0 = (wid & 3) * 2048 + (wid >> 2) * 512 + lane * 8;
  const u16* srcA0 = A  + (long)(m0 + (wid >> 2) * 64 + lane) * LDA + kstart + (wid & 3) * 8;
  const u16* srcA1 = srcA0 + (long)128 * LDA;
  const u16* srcB0 = Bt + (long)(n0 + (wid >> 2) * 64 + lane) * LDA + kstart + (wid & 3) * 8;
  const u16* srcB1 = srcB0 + (long)128 * LDA;

#define STAGE_A(t, s) do { \
    gload16(srcA0 + (t) * 32, &lds[(s) * SLOT + doff0]); \
    gload16(srcA1 + (t) * 32, &lds[(s) * SLOT + doff0 + 1024]); } while (0)
#define STAGE_B(t, s) do { \
    gload16(srcB0 + (t) * 32, &lds[(s) * SLOT + 8192 + doff0]); \
    gload16(srcB1 + (t) * 32, &lds[(s) * SLOT + 8192 + doff0 + 1024]); } while (0)

  // ---- fragment read offsets (u16 units) ----
  // addr = plane(lane>>4)*2048 + row*8 ; row_A = wr*128 + m*16 + (lane&15)
  const int aoff = (lane >> 4) * 2048 + (wr * 128 + (lane & 15)) * 8;
  const int boff = (lane >> 4) * 2048 + (wc * 64  + (lane & 15)) * 8;

  f32x4_t acc[8][4];
#pragma unroll
  for (int m = 0; m < 8; ++m)
#pragma unroll
    for (int n = 0; n < 4; ++n) acc[m][n] = (f32x4_t){0.f, 0.f, 0.f, 0.f};

  // ---- prologue: stage tiles 0 and 1 (NT >= 64 for all shapes here) ----
  STAGE_A(0, 0); STAGE_B(0, 0);
  STAGE_A(1, 1); STAGE_B(1, 1);
  asm volatile("s_waitcnt vmcnt(4)" ::: "memory");   // tile 0 resident
  __builtin_amdgcn_s_barrier();

  int slot = 0, s2 = 2;
  for (int t = 0; t < NT; ++t) {
    const u16* sA = &lds[slot * SLOT];
    const u16* sB = sA + 8192;
    const bool pre = (t + 2 < NT);

    // ---------------- phase 0: B frags + A frags m0..3, stage A(t+2) ----------------
    bf16x8_t bv[4], av[4];
#pragma unroll
    for (int n = 0; n < 4; ++n) bv[n] = *(const bf16x8_t*)&sB[boff + n * 128];
#pragma unroll
    for (int m = 0; m < 4; ++m) av[m] = *(const bf16x8_t*)&sA[aoff + m * 128];
    if (pre) STAGE_A(t + 2, s2);
    __builtin_amdgcn_s_barrier();
    asm volatile("s_waitcnt lgkmcnt(0)" ::: "memory");
    __builtin_amdgcn_sched_barrier(0);
    __builtin_amdgcn_s_setprio(1);
#pragma unroll
    for (int m = 0; m < 4; ++m)
#pragma unroll
      for (int n = 0; n < 4; ++n)
        acc[m][n] = __builtin_amdgcn_mfma_f32_16x16x32_bf16(av[m], bv[n], acc[m][n], 0, 0, 0);
    __builtin_amdgcn_s_setprio(0);
    __builtin_amdgcn_s_barrier();

    // ---------------- phase 1: A frags m4..7, stage B(t+2), boundary vmcnt ----------------
#pragma unroll
    for (int m = 0; m < 4; ++m) av[m] = *(const bf16x8_t*)&sA[aoff + 512 + m * 128];
    if (pre) STAGE_B(t + 2, s2);
    __builtin_amdgcn_s_barrier();
    asm volatile("s_waitcnt lgkmcnt(0)" ::: "memory");
    __builtin_amdgcn_sched_barrier(0);
    __builtin_amdgcn_s_setprio(1);
#pragma unroll
    for (int m = 0; m < 4; ++m)
#pragma unroll
      for (int n = 0; n < 4; ++n)
        acc[m + 4][n] = __builtin_amdgcn_mfma_f32_16x16x32_bf16(av[m], bv[n], acc[m + 4][n], 0, 0, 0);
    __builtin_amdgcn_s_setprio(0);
    if (pre) asm volatile("s_waitcnt vmcnt(4)" ::: "memory");  // tile t+1 resident, t+2 in flight
    else     asm volatile("s_waitcnt vmcnt(0)" ::: "memory");  // epilogue drain (last 2 tiles)
    __builtin_amdgcn_s_barrier();

    slot = (slot == 2) ? 0 : slot + 1;
    s2   = (s2   == 2) ? 0 : s2   + 1;
  }
#undef STAGE_A
#undef STAGE_B

  // ---- epilogue: C/D layout col=lane&15, row=(lane>>4)*4+reg ----
  const int lr4 = (lane >> 4) * 4;
  const int lc  = lane & 15;
#pragma unroll
  for (int m = 0; m < 8; ++m) {
    int rg = m0 + wr * 128 + m * 16 + lr4;
#pragma unroll
    for (int n = 0; n < 4; ++n) {
      int cg = n0 + wc * 64 + n * 16 + lc;
#pragma unroll
      for (int r = 0; r < 4; ++r)
        Cout[(long)(rg + r) * NCOL + cg] = f2b(acc[m][n][r]);
    }
  }
}

// ---------- pass2: gates -> c_new (fp32 out), A2 = [bf16(c_new) | bf16(tanh(c_new))] ----------
__global__ void pass2_kernel(const u16* __restrict__ G1, const float* __restrict__ c_t,
                             const float* __restrict__ bias_i, const float* __restrict__ bias_f,
                             const float* __restrict__ bias_c,
                             float* __restrict__ c_new_out, u16* __restrict__ A2) {
  long i = (long)blockIdx.x * blockDim.x + threadIdx.x;
  long e = i * 8;
  int b = (int)(e >> 11);
  int j = (int)(e & 2047);
  const u16* row = G1 + (long)b * 8192;
  u16x8_t ip = *(const u16x8_t*)(row + j);
  u16x8_t fp = *(const u16x8_t*)(row + 2048 + j);
  u16x8_t gp = *(const u16x8_t*)(row + 4096 + j);
  f32x8_t cp = *(const f32x8_t*)(c_t + (long)b * 2048 + j);
  f32x8_t bi = *(const f32x8_t*)(bias_i + j);
  f32x8_t bf = *(const f32x8_t*)(bias_f + j);
  f32x8_t bc = *(const f32x8_t*)(bias_c + j);

  f32x8_t cn;
  u16x8_t cb, rb;
#pragma unroll
  for (int r = 0; r < 8; ++r) {
    float ig = sigm_(b2f(ip[r]) + bi[r]);
    float fg = sigm_(b2f(fp[r]) + bf[r]);
    float g  = tanh_(b2f(gp[r]) + bc[r]);
    float c  = fg * cp[r] + ig * g;
    cn[r] = c;
    cb[r] = f2b(c);
    rb[r] = f2b(tanh_(c));
  }
  *(f32x8_t*)(c_new_out + (long)b * 2048 + j) = cn;
  u16* a2row = A2 + (long)b * 4096;
  *(u16x8_t*)(a2row + j) = cb;
  *(u16x8_t*)(a2row + 2048 + j) = rb;
}

// ---------- pass3: h_new = sigmoid(og_pre + c@Woc + bias_o) * (m_t + xr) ----------
__global__ void pass3_kernel(const u16* __restrict__ G1, const u16* __restrict__ G2,
                             const float* __restrict__ bias_o, float* __restrict__ h_out) {
  long i = (long)blockIdx.x * blockDim.x + threadIdx.x;
  long e = i * 8;
  int b = (int)(e >> 10);
  int j = (int)(e & 1023);
  const u16* row1 = G1 + (long)b * 8192;
  const u16* row2 = G2 + (long)b * 2048;
  u16x8_t ogp = *(const u16x8_t*)(row1 + 6144 + j);
  u16x8_t xrp = *(const u16x8_t*)(row1 + 7168 + j);
  u16x8_t ocg = *(const u16x8_t*)(row2 + j);
  u16x8_t mt  = *(const u16x8_t*)(row2 + 1024 + j);
  f32x8_t bo  = *(const f32x8_t*)(bias_o + j);
  f32x8_t h;
#pragma unroll
  for (int r = 0; r < 8; ++r) {
    float og = sigm_(b2f(ogp[r]) + b2f(ocg[r]) + bo[r]);
    h[r] = og * (b2f(mt[r]) + b2f(xrp[r]));
  }
  *(f32x8_t*)(h_out + (long)b * 1024 + j) = h;
}

// ---------- launch ----------
extern "C" void kernel_launch(void* const* d_in, const int* in_sizes, int n_in,
                              void* d_out, int out_size, void* d_ws, size_t ws_size,
                              hipStream_t stream) {
  const float* x_t      = (const float*)d_in[0];
  const float* h_t      = (const float*)d_in[1];
  const float* c_t      = (const float*)d_in[2];
  const float* w_if_x   = (const float*)d_in[3];
  const float* w_if_h   = (const float*)d_in[4];
  const float* w_if_c   = (const float*)d_in[5];
  const float* bias_i   = (const float*)d_in[6];
  const float* bias_f   = (const float*)d_in[7];
  const float* w_c_x    = (const float*)d_in[8];
  const float* w_c_h    = (const float*)d_in[9];
  const float* bias_c   = (const float*)d_in[10];
  const float* w_o_x    = (const float*)d_in[11];
  const float* w_o_h    = (const float*)d_in[12];
  const float* w_o_c    = (const float*)d_in[13];
  const float* bias_o   = (const float*)d_in[14];
  const float* w_r_proj = (const float*)d_in[15];
  const float* w_r_x    = (const float*)d_in[16];

  char* ws = (char*)d_ws;
  u16* A1  = (u16*)(ws);
  u16* W1t = (u16*)(ws + 167772160L);
  u16* G1  = (u16*)(ws + 251658240L);
  u16* W2t = (u16*)(ws + 520093696L);
  u16* A2  = (u16*)(ws);               // aliases A1 (dead after GEMM1)
  u16* G2  = (u16*)(ws + 167772160L);  // aliases W1t (dead after GEMM1)

  float* h_out = (float*)d_out;
  float* c_out = h_out + 16384L * 1024L;

  // --- stage 0: conversions ---
  cvt_act_kernel<<<32768, 256, 0, stream>>>(x_t, A1, 2048, 5120, 0);
  cvt_act_kernel<<<16384, 256, 0, stream>>>(h_t, A1, 1024, 5120, 2048);
  cvt_act_kernel<<<32768, 256, 0, stream>>>(c_t, A1, 2048, 5120, 3072);

  dim3 tb(32, 8);
  cvt_wt_kernel<<<dim3(4096 / 32, 2048 / 32), tb, 0, stream>>>(w_if_x,   W1t, 2048, 4096, 5120, 0,    0);
  cvt_wt_kernel<<<dim3(4096 / 32, 1024 / 32), tb, 0, stream>>>(w_if_h,   W1t, 1024, 4096, 5120, 0,    2048);
  cvt_wt_kernel<<<dim3(4096 / 32, 2048 / 32), tb, 0, stream>>>(w_if_c,   W1t, 2048, 4096, 5120, 0,    3072);
  cvt_wt_kernel<<<dim3(2048 / 32, 2048 / 32), tb, 0, stream>>>(w_c_x,    W1t, 2048, 2048, 5120, 4096, 0);
  cvt_wt_kernel<<<dim3(2048 / 32, 1024 / 32), tb, 0, stream>>>(w_c_h,    W1t, 1024, 2048, 5120, 4096, 2048);
  cvt_wt_kernel<<<dim3(1024 / 32, 2048 / 32), tb, 0, stream>>>(w_o_x,    W1t, 2048, 1024, 5120, 6144, 0);
  cvt_wt_kernel<<<dim3(1024 / 32, 1024 / 32), tb, 0, stream>>>(w_o_h,    W1t, 1024, 1024, 5120, 6144, 2048);
  cvt_wt_kernel<<<dim3(1024 / 32, 2048 / 32), tb, 0, stream>>>(w_r_x,    W1t, 2048, 1024, 5120, 7168, 0);
  cvt_wt_kernel<<<dim3(1024 / 32, 2048 / 32), tb, 0, stream>>>(w_o_c,    W2t, 2048, 1024, 4096, 0,    0);
  cvt_wt_kernel<<<dim3(1024 / 32, 2048 / 32), tb, 0, stream>>>(w_r_proj, W2t, 2048, 1024, 4096, 1024, 2048);

  // --- stage 1: big fused GEMM -> all pre-activations ---
  gemm256_kernel<0><<<2048, 512, 0, stream>>>(A1, W1t, G1);

  // --- stage 2: elementwise gates -> c_new + A2 ---
  pass2_kernel<<<16384, 256, 0, stream>>>(G1, c_t, bias_i, bias_f, bias_c, c_out, A2);

  // --- stage 3: [c_new|r_t] GEMM -> og peephole + m_t ---
  gemm256_kernel<1><<<512, 512, 0, stream>>>(A2, W2t, G2);

  // --- stage 4: h_new ---
  pass3_kernel<<<8192, 256, 0, stream>>>(G1, G2, bias_o, h_out);
}

// Round 3
// 1510.530 us; speedup vs baseline: 1.3598x; 1.2333x over previous
//
#include <hip/hip_runtime.h>
#include <hip/hip_bf16.h>
#include <math.h>

typedef unsigned short u16;
typedef __bf16 bf16x8_t __attribute__((ext_vector_type(8)));
typedef float  f32x4_t  __attribute__((ext_vector_type(4)));
typedef float  f32x8_t  __attribute__((ext_vector_type(8)));
typedef u16    u16x4_t  __attribute__((ext_vector_type(4)));
typedef u16    u16x8_t  __attribute__((ext_vector_type(8)));

// ---------- helpers ----------
__device__ __forceinline__ u16 f2b(float f) {
  unsigned u = __builtin_bit_cast(unsigned, f);
  u += 0x7fffu + ((u >> 16) & 1u);      // RNE; inputs are finite
  return (u16)(u >> 16);
}
__device__ __forceinline__ float b2f(u16 h) {
  unsigned u = ((unsigned)h) << 16;
  return __builtin_bit_cast(float, u);
}
__device__ __forceinline__ float sigm_(float x) { return 1.0f / (1.0f + __expf(-x)); }
__device__ __forceinline__ float tanh_(float x) { return 1.0f - 2.0f / (__expf(2.0f * x) + 1.0f); }

__device__ __forceinline__ void gload16(const void* g, void* l) {
  __builtin_amdgcn_global_load_lds(
      (__attribute__((address_space(1))) void*)(g),
      (__attribute__((address_space(3))) void*)(l), 16, 0, 0);
}

// ==========================================================================
// Packed panel format: tiles of 256 rows x 32 k, 16 KB each, laid out as
//   [k-plane p=0..3][row 0..255][8 u16]   (plane = k sub-slice of 8)
// Panel = [row_block][k_tile][tile(8192 u16)], k-tile stride = KT per panel.
// Staging a tile = 16 contiguous 1KB wave-loads (fully coalesced), LDS image
// identical to the packed tile -> conflict-free ds_read_b128 fragments.
// ==========================================================================

// ---------- pack fp32 activations [B,C] -> packed bf16 panel (col offset c0) ----------
// grid: (row_blocks=64, C/32), block 256. One block packs one 256x32 tile.
__global__ void cvt_act_kernel(const float* __restrict__ src, u16* __restrict__ dst,
                               int C, int KT, int c0) {
  int mb = blockIdx.x, ktl = blockIdx.y, t = threadIdx.x;
  int ktg = (c0 >> 5) + ktl;
  const float* s = src + (long)(mb * 256 + t) * C + ktl * 32;
  u16* d = dst + ((long)(mb * KT + ktg)) * 8192 + t * 8;
#pragma unroll
  for (int p = 0; p < 4; ++p) {
    f32x8_t v = *(const f32x8_t*)(s + p * 8);
    u16x8_t o;
#pragma unroll
    for (int r = 0; r < 8; ++r) o[r] = f2b(v[r]);
    *(u16x8_t*)(d + p * 2048) = o;
  }
}

// ---------- pack fp32 weight [K,N] (transposed) -> packed bf16 panel ----------
// grid: (N/256, K/32), block 256. thread t = output row (column n of W).
__global__ void cvt_wt_kernel(const float* __restrict__ src, u16* __restrict__ dst,
                              int N, int KT, int n0, int k0) {
  int bx = blockIdx.x, by = blockIdx.y, t = threadIdx.x;
  int n = bx * 256 + t;
  int nb_g = (n0 >> 8) + bx;
  int ktg = (k0 >> 5) + by;
  float tmp[32];
#pragma unroll
  for (int kk = 0; kk < 32; ++kk)
    tmp[kk] = src[(long)(by * 32 + kk) * N + n];
  u16* d = dst + ((long)(nb_g * KT + ktg)) * 8192 + t * 8;
#pragma unroll
  for (int p = 0; p < 4; ++p) {
    u16x8_t o;
#pragma unroll
    for (int r = 0; r < 8; ++r) o[r] = f2b(tmp[p * 8 + r]);
    *(u16x8_t*)(d + p * 2048) = o;
  }
}

// ==========================================================================
// 256x256 deep-pipelined bf16 GEMM (T3+T4+T5), BK=32, 8 waves (2M x 4N).
// LDS: 3-slot ring x (A 16KB + B 16KB) = 96 KiB. Packed-panel staging.
// MODE 0: A1p[64mb x 160kt] x W1tp[32nb x 160kt] -> G1 bf16 [16384,8192]
//         NT per nb: nb<16 -> 160, nb<28 -> 96, else 64 (segmented K)
// MODE 1: A2p[64mb x 128kt] x W2tp[8nb x 128kt]  -> G2 bf16 [16384,2048]
//         nb<4: kt 0..63 (c_new part), else kt 64..127 (r_t part)
// ==========================================================================
template <int MODE>
__global__ __launch_bounds__(512, 2) void gemm256_kernel(
    const u16* __restrict__ A, const u16* __restrict__ Bt, u16* __restrict__ Cout) {
  constexpr int KT   = (MODE == 0) ? 160 : 128;
  constexpr int NCOL = (MODE == 0) ? 8192 : 2048;
  constexpr int NBN  = NCOL / 256;
  constexpr int SLOT = 16384;   // u16 per ring slot (A 8192 + B 8192)

  __shared__ u16 lds[3 * SLOT];  // 96 KiB

  // XCD-bijective swizzle (grid % 8 == 0 in both modes)
  int bid = blockIdx.x;
  int cpx = gridDim.x >> 3;
  bid = (bid & 7) * cpx + (bid >> 3);

  int mb = bid / NBN, nb = bid % NBN;
  int m0 = mb * 256, n0 = nb * 256;

  int kt0, NT;
  if (MODE == 0) { kt0 = 0; NT = (nb < 16) ? 160 : ((nb < 28) ? 96 : 64); }
  else           { kt0 = (nb < 4) ? 0 : 64; NT = 64; }

  const int tid  = threadIdx.x;
  const int lane = tid & 63;
  const int wid  = tid >> 6;       // 0..7
  const int wr   = wid >> 2;       // 0..1  (wave row: 128 output rows)
  const int wc   = wid & 3;        // 0..3  (wave col: 64 output cols)

  // staging: wave w copies segments w and w+8 (1KB each) of the 16KB tile
  const int segoff = wid * 512 + lane * 8;            // u16 units; +4096 for seg1
  const u16* baseA = A  + ((long)(mb * KT + kt0)) * 8192 + segoff;
  const u16* baseB = Bt + ((long)(nb * KT + kt0)) * 8192 + segoff;

#define STAGE_A(t, s) do { \
    gload16(baseA + (long)(t) * 8192,        &lds[(s) * SLOT + segoff]); \
    gload16(baseA + (long)(t) * 8192 + 4096, &lds[(s) * SLOT + segoff + 4096]); } while (0)
#define STAGE_B(t, s) do { \
    gload16(baseB + (long)(t) * 8192,        &lds[(s) * SLOT + 8192 + segoff]); \
    gload16(baseB + (long)(t) * 8192 + 4096, &lds[(s) * SLOT + 8192 + segoff + 4096]); } while (0)

  // fragment read offsets (u16): plane(lane>>4)*2048 + row*8
  const int aoff = (lane >> 4) * 2048 + (wr * 128 + (lane & 15)) * 8;
  const int boff = (lane >> 4) * 2048 + (wc * 64  + (lane & 15)) * 8;

  f32x4_t acc[8][4];
#pragma unroll
  for (int m = 0; m < 8; ++m)
#pragma unroll
    for (int n = 0; n < 4; ++n) acc[m][n] = (f32x4_t){0.f, 0.f, 0.f, 0.f};

  // prologue: stage tiles 0 and 1
  STAGE_A(0, 0); STAGE_B(0, 0);
  STAGE_A(1, 1); STAGE_B(1, 1);
  asm volatile("s_waitcnt vmcnt(4)" ::: "memory");   // tile 0 resident
  __builtin_amdgcn_s_barrier();

  int slot = 0, s2 = 2;
  for (int t = 0; t < NT; ++t) {
    const u16* sA = &lds[slot * SLOT];
    const u16* sB = sA + 8192;
    const bool pre = (t + 2 < NT);

    // ---- phase 0: B frags + A frags m0..3, stage A(t+2) ----
    bf16x8_t bv[4], av[4];
#pragma unroll
    for (int n = 0; n < 4; ++n) bv[n] = *(const bf16x8_t*)&sB[boff + n * 128];
#pragma unroll
    for (int m = 0; m < 4; ++m) av[m] = *(const bf16x8_t*)&sA[aoff + m * 128];
    if (pre) STAGE_A(t + 2, s2);
    __builtin_amdgcn_s_barrier();
    asm volatile("s_waitcnt lgkmcnt(0)" ::: "memory");
    __builtin_amdgcn_sched_barrier(0);
    __builtin_amdgcn_s_setprio(1);
#pragma unroll
    for (int m = 0; m < 4; ++m)
#pragma unroll
      for (int n = 0; n < 4; ++n)
        acc[m][n] = __builtin_amdgcn_mfma_f32_16x16x32_bf16(av[m], bv[n], acc[m][n], 0, 0, 0);
    __builtin_amdgcn_s_setprio(0);
    __builtin_amdgcn_s_barrier();

    // ---- phase 1: A frags m4..7, stage B(t+2), boundary vmcnt ----
#pragma unroll
    for (int m = 0; m < 4; ++m) av[m] = *(const bf16x8_t*)&sA[aoff + 512 + m * 128];
    if (pre) STAGE_B(t + 2, s2);
    __builtin_amdgcn_s_barrier();
    asm volatile("s_waitcnt lgkmcnt(0)" ::: "memory");
    __builtin_amdgcn_sched_barrier(0);
    __builtin_amdgcn_s_setprio(1);
#pragma unroll
    for (int m = 0; m < 4; ++m)
#pragma unroll
      for (int n = 0; n < 4; ++n)
        acc[m + 4][n] = __builtin_amdgcn_mfma_f32_16x16x32_bf16(av[m], bv[n], acc[m + 4][n], 0, 0, 0);
    __builtin_amdgcn_s_setprio(0);
    if (pre) asm volatile("s_waitcnt vmcnt(4)" ::: "memory");  // t+1 resident, t+2 in flight
    else     asm volatile("s_waitcnt vmcnt(0)" ::: "memory");  // epilogue drain
    __builtin_amdgcn_s_barrier();

    slot = (slot == 2) ? 0 : slot + 1;
    s2   = (s2   == 2) ? 0 : s2   + 1;
  }
#undef STAGE_A
#undef STAGE_B

  // epilogue: C/D layout col=lane&15, row=(lane>>4)*4+reg
  const int lr4 = (lane >> 4) * 4;
  const int lc  = lane & 15;
#pragma unroll
  for (int m = 0; m < 8; ++m) {
    int rg = m0 + wr * 128 + m * 16 + lr4;
#pragma unroll
    for (int n = 0; n < 4; ++n) {
      int cg = n0 + wc * 64 + n * 16 + lc;
#pragma unroll
      for (int r = 0; r < 4; ++r)
        Cout[(long)(rg + r) * NCOL + cg] = f2b(acc[m][n][r]);
    }
  }
}

// ---------- pass2: gates -> c_new (fp32), A2 packed = [bf16(c_new) | bf16(tanh(c_new))] ----------
// grid: (mb=64, jg=64), block 256; thread t = row within mb; cols jg*32..+31.
__global__ void pass2_kernel(const u16* __restrict__ G1, const float* __restrict__ c_t,
                             const float* __restrict__ bias_i, const float* __restrict__ bias_f,
                             const float* __restrict__ bias_c,
                             float* __restrict__ c_new_out, u16* __restrict__ A2p) {
  int mb = blockIdx.x, jg = blockIdx.y, t = threadIdx.x;
  int b = mb * 256 + t;
  int j0 = jg * 32;
  const u16* row = G1 + (long)b * 8192 + j0;
  const float* cp_p = c_t + (long)b * 2048 + j0;
  float* co_p = c_new_out + (long)b * 2048 + j0;
  // A2 packed: c part -> kt=jg, r part -> kt=64+jg  (KT=128)
  u16* dc = A2p + ((long)(mb * 128 + jg)) * 8192 + t * 8;
  u16* dr = dc + (long)64 * 8192;

#pragma unroll
  for (int q = 0; q < 4; ++q) {
    u16x8_t ip = *(const u16x8_t*)(row + q * 8);
    u16x8_t fp = *(const u16x8_t*)(row + 2048 + q * 8);
    u16x8_t gp = *(const u16x8_t*)(row + 4096 + q * 8);
    f32x8_t cp = *(const f32x8_t*)(cp_p + q * 8);
    f32x8_t bi = *(const f32x8_t*)(bias_i + j0 + q * 8);
    f32x8_t bf = *(const f32x8_t*)(bias_f + j0 + q * 8);
    f32x8_t bc = *(const f32x8_t*)(bias_c + j0 + q * 8);
    f32x8_t cn;
    u16x8_t cb, rb;
#pragma unroll
    for (int r = 0; r < 8; ++r) {
      float ig = sigm_(b2f(ip[r]) + bi[r]);
      float fg = sigm_(b2f(fp[r]) + bf[r]);
      float g  = tanh_(b2f(gp[r]) + bc[r]);
      float c  = fg * cp[r] + ig * g;
      cn[r] = c;
      cb[r] = f2b(c);
      rb[r] = f2b(tanh_(c));
    }
    *(f32x8_t*)(co_p + q * 8) = cn;
    *(u16x8_t*)(dc + q * 2048) = cb;
    *(u16x8_t*)(dr + q * 2048) = rb;
  }
}

// ---------- pass3: h_new = sigmoid(og_pre + c@Woc + bias_o) * (m_t + xr) ----------
__global__ void pass3_kernel(const u16* __restrict__ G1, const u16* __restrict__ G2,
                             const float* __restrict__ bias_o, float* __restrict__ h_out) {
  long i = (long)blockIdx.x * blockDim.x + threadIdx.x;
  long e = i * 8;
  int b = (int)(e >> 10);
  int j = (int)(e & 1023);
  const u16* row1 = G1 + (long)b * 8192;
  const u16* row2 = G2 + (long)b * 2048;
  u16x8_t ogp = *(const u16x8_t*)(row1 + 6144 + j);
  u16x8_t xrp = *(const u16x8_t*)(row1 + 7168 + j);
  u16x8_t ocg = *(const u16x8_t*)(row2 + j);
  u16x8_t mt  = *(const u16x8_t*)(row2 + 1024 + j);
  f32x8_t bo  = *(const f32x8_t*)(bias_o + j);
  f32x8_t h;
#pragma unroll
  for (int r = 0; r < 8; ++r) {
    float og = sigm_(b2f(ogp[r]) + b2f(ocg[r]) + bo[r]);
    h[r] = og * (b2f(mt[r]) + b2f(xrp[r]));
  }
  *(f32x8_t*)(h_out + (long)b * 1024 + j) = h;
}

// ---------- launch ----------
extern "C" void kernel_launch(void* const* d_in, const int* in_sizes, int n_in,
                              void* d_out, int out_size, void* d_ws, size_t ws_size,
                              hipStream_t stream) {
  const float* x_t      = (const float*)d_in[0];
  const float* h_t      = (const float*)d_in[1];
  const float* c_t      = (const float*)d_in[2];
  const float* w_if_x   = (const float*)d_in[3];
  const float* w_if_h   = (const float*)d_in[4];
  const float* w_if_c   = (const float*)d_in[5];
  const float* bias_i   = (const float*)d_in[6];
  const float* bias_f   = (const float*)d_in[7];
  const float* w_c_x    = (const float*)d_in[8];
  const float* w_c_h    = (const float*)d_in[9];
  const float* bias_c   = (const float*)d_in[10];
  const float* w_o_x    = (const float*)d_in[11];
  const float* w_o_h    = (const float*)d_in[12];
  const float* w_o_c    = (const float*)d_in[13];
  const float* bias_o   = (const float*)d_in[14];
  const float* w_r_proj = (const float*)d_in[15];
  const float* w_r_x    = (const float*)d_in[16];

  char* ws = (char*)d_ws;
  // layout (512 MiB):
  //   A1p  [64][160][8192]u16 @ 0        (160 MiB)
  //   W1tp [32][160][8192]u16 @ 160 MiB  ( 80 MiB)
  //   G1   [16384,8192] bf16 @ 240 MiB   (256 MiB)
  //   W2tp [8][128][8192]u16 @ 496 MiB   ( 16 MiB)
  //   A2p  [64][128][8192]u16 @ 0        (aliases A1p, dead after GEMM1)
  //   G2   [16384,2048] bf16 @ 160 MiB   (aliases W1tp, dead after GEMM1)
  u16* A1p  = (u16*)(ws);
  u16* W1tp = (u16*)(ws + 167772160L);
  u16* G1   = (u16*)(ws + 251658240L);
  u16* W2tp = (u16*)(ws + 520093696L);
  u16* A2p  = (u16*)(ws);
  u16* G2   = (u16*)(ws + 167772160L);

  float* h_out = (float*)d_out;
  float* c_out = h_out + 16384L * 1024L;

  // --- stage 0: pack activations (A1 panel k-map: x 0..63, h 64..95, c 96..159) ---
  cvt_act_kernel<<<dim3(64, 64), 256, 0, stream>>>(x_t, A1p, 2048, 160, 0);
  cvt_act_kernel<<<dim3(64, 32), 256, 0, stream>>>(h_t, A1p, 1024, 160, 2048);
  cvt_act_kernel<<<dim3(64, 64), 256, 0, stream>>>(c_t, A1p, 2048, 160, 3072);

  // --- pack weights (transposed) ---
  cvt_wt_kernel<<<dim3(16, 64), 256, 0, stream>>>(w_if_x,   W1tp, 4096, 160, 0,    0);
  cvt_wt_kernel<<<dim3(16, 32), 256, 0, stream>>>(w_if_h,   W1tp, 4096, 160, 0,    2048);
  cvt_wt_kernel<<<dim3(16, 64), 256, 0, stream>>>(w_if_c,   W1tp, 4096, 160, 0,    3072);
  cvt_wt_kernel<<<dim3(8,  64), 256, 0, stream>>>(w_c_x,    W1tp, 2048, 160, 4096, 0);
  cvt_wt_kernel<<<dim3(8,  32), 256, 0, stream>>>(w_c_h,    W1tp, 2048, 160, 4096, 2048);
  cvt_wt_kernel<<<dim3(4,  64), 256, 0, stream>>>(w_o_x,    W1tp, 1024, 160, 6144, 0);
  cvt_wt_kernel<<<dim3(4,  32), 256, 0, stream>>>(w_o_h,    W1tp, 1024, 160, 6144, 2048);
  cvt_wt_kernel<<<dim3(4,  64), 256, 0, stream>>>(w_r_x,    W1tp, 1024, 160, 7168, 0);
  cvt_wt_kernel<<<dim3(4,  64), 256, 0, stream>>>(w_o_c,    W2tp, 1024, 128, 0,    0);
  cvt_wt_kernel<<<dim3(4,  64), 256, 0, stream>>>(w_r_proj, W2tp, 1024, 128, 1024, 2048);

  // --- stage 1: big fused GEMM -> all pre-activations ---
  gemm256_kernel<0><<<2048, 512, 0, stream>>>(A1p, W1tp, G1);

  // --- stage 2: elementwise gates -> c_new + packed A2 ---
  pass2_kernel<<<dim3(64, 64), 256, 0, stream>>>(G1, c_t, bias_i, bias_f, bias_c, c_out, A2p);

  // --- stage 3: [c_new|r_t] GEMM -> og peephole + m_t ---
  gemm256_kernel<1><<<512, 512, 0, stream>>>(A2p, W2tp, G2);

  // --- stage 4: h_new ---
  pass3_kernel<<<8192, 256, 0, stream>>>(G1, G2, bias_o, h_out);
}

// Round 4
// 1500.546 us; speedup vs baseline: 1.3688x; 1.0067x over previous
//
#include <hip/hip_runtime.h>
#include <hip/hip_bf16.h>
#include <math.h>

typedef unsigned short u16;
typedef __bf16 bf16x8_t __attribute__((ext_vector_type(8)));
typedef float  f32x4_t  __attribute__((ext_vector_type(4)));
typedef float  f32x8_t  __attribute__((ext_vector_type(8)));
typedef u16    u16x4_t  __attribute__((ext_vector_type(4)));
typedef u16    u16x8_t  __attribute__((ext_vector_type(8)));

// ---------- helpers ----------
__device__ __forceinline__ u16 f2b(float f) {
  unsigned u = __builtin_bit_cast(unsigned, f);
  u += 0x7fffu + ((u >> 16) & 1u);      // RNE; inputs are finite
  return (u16)(u >> 16);
}
__device__ __forceinline__ float b2f(u16 h) {
  unsigned u = ((unsigned)h) << 16;
  return __builtin_bit_cast(float, u);
}
__device__ __forceinline__ float sigm_(float x) { return 1.0f / (1.0f + __expf(-x)); }
__device__ __forceinline__ float tanh_(float x) { return 1.0f - 2.0f / (__expf(2.0f * x) + 1.0f); }

__device__ __forceinline__ void gload16(const void* g, void* l) {
  __builtin_amdgcn_global_load_lds(
      (__attribute__((address_space(1))) void*)(g),
      (__attribute__((address_space(3))) void*)(l), 16, 0, 0);
}

// ==========================================================================
// Packed panel format: tiles of 256 rows x 32 k, 16 KB each, laid out as
//   [k-plane p=0..3][row 0..255][8 u16]   (plane = k sub-slice of 8)
// Panel = [row_block][k_tile][tile(8192 u16)], k-tile stride = KT per panel.
// Staging a tile = 16 contiguous 1KB wave-loads (fully coalesced), LDS image
// identical to the packed tile -> conflict-free ds_read_b128 fragments.
// ==========================================================================

// ---------- pack fp32 activations [B,C] -> packed bf16 panel (col offset c0) ----------
__global__ void cvt_act_kernel(const float* __restrict__ src, u16* __restrict__ dst,
                               int C, int KT, int c0) {
  int mb = blockIdx.x, ktl = blockIdx.y, t = threadIdx.x;
  int ktg = (c0 >> 5) + ktl;
  const float* s = src + (long)(mb * 256 + t) * C + ktl * 32;
  u16* d = dst + ((long)(mb * KT + ktg)) * 8192 + t * 8;
#pragma unroll
  for (int p = 0; p < 4; ++p) {
    f32x8_t v = *(const f32x8_t*)(s + p * 8);
    u16x8_t o;
#pragma unroll
    for (int r = 0; r < 8; ++r) o[r] = f2b(v[r]);
    *(u16x8_t*)(d + p * 2048) = o;
  }
}

// ---------- pack fp32 weight [K,N] (transposed) -> packed bf16 panel ----------
__global__ void cvt_wt_kernel(const float* __restrict__ src, u16* __restrict__ dst,
                              int N, int KT, int n0, int k0) {
  int bx = blockIdx.x, by = blockIdx.y, t = threadIdx.x;
  int n = bx * 256 + t;
  int nb_g = (n0 >> 8) + bx;
  int ktg = (k0 >> 5) + by;
  float tmp[32];
#pragma unroll
  for (int kk = 0; kk < 32; ++kk)
    tmp[kk] = src[(long)(by * 32 + kk) * N + n];
  u16* d = dst + ((long)(nb_g * KT + ktg)) * 8192 + t * 8;
#pragma unroll
  for (int p = 0; p < 4; ++p) {
    u16x8_t o;
#pragma unroll
    for (int r = 0; r < 8; ++r) o[r] = f2b(tmp[p * 8 + r]);
    *(u16x8_t*)(d + p * 2048) = o;
  }
}

// ==========================================================================
// 256x256 deep-pipelined bf16 GEMM, BK=32, 8 waves (2M x 4N), packed panels.
// One barrier per K-tile; compiler emits counted lgkmcnt to interleave
// ds_read with the 32-MFMA cluster. Operands SWAPPED (W-frag as A-op,
// X-frag as B-op) so each lane's 4 acc regs are 4 consecutive OUTPUT COLS
// -> u16x4 epilogue stores.
// MODE 0: A1p[64mb x 160kt] x W1tp[32nb x 160kt] -> G1 bf16 [16384,8192]
//         NT per nb: nb<16 -> 160, nb<28 -> 96, else 64 (segmented K)
// MODE 1: A2p[64mb x 128kt] x W2tp[8nb x 128kt]  -> G2 bf16 [16384,2048]
//         nb<4: kt 0..63 (c_new part), else kt 64..127 (r_t part)
// ==========================================================================
template <int MODE>
__global__ __launch_bounds__(512, 2) void gemm256_kernel(
    const u16* __restrict__ A, const u16* __restrict__ Bt, u16* __restrict__ Cout) {
  constexpr int KT   = (MODE == 0) ? 160 : 128;
  constexpr int NCOL = (MODE == 0) ? 8192 : 2048;
  constexpr int NBN  = NCOL / 256;
  constexpr int SLOT = 16384;   // u16 per ring slot (A 8192 + B 8192)

  __shared__ u16 lds[3 * SLOT];  // 96 KiB

  // XCD-bijective swizzle (grid % 8 == 0 in both modes)
  int bid = blockIdx.x;
  int cpx = gridDim.x >> 3;
  bid = (bid & 7) * cpx + (bid >> 3);

  int mb = bid / NBN, nb = bid % NBN;
  int m0 = mb * 256, n0 = nb * 256;

  int kt0, NT;
  if (MODE == 0) { kt0 = 0; NT = (nb < 16) ? 160 : ((nb < 28) ? 96 : 64); }
  else           { kt0 = (nb < 4) ? 0 : 64; NT = 64; }

  const int tid  = threadIdx.x;
  const int lane = tid & 63;
  const int wid  = tid >> 6;       // 0..7
  const int wr   = wid >> 2;       // 0..1  (wave row: 128 output rows)
  const int wc   = wid & 3;        // 0..3  (wave col: 64 output cols)

  // staging: wave w copies segments w and w+8 (1KB each) of the 16KB tile
  const int segoff = wid * 512 + lane * 8;            // u16 units; +4096 for seg1
  const u16* baseA = A  + ((long)(mb * KT + kt0)) * 8192 + segoff;
  const u16* baseB = Bt + ((long)(nb * KT + kt0)) * 8192 + segoff;

#define STAGE_A(t, s) do { \
    gload16(baseA + (long)(t) * 8192,        &lds[(s) * SLOT + segoff]); \
    gload16(baseA + (long)(t) * 8192 + 4096, &lds[(s) * SLOT + segoff + 4096]); } while (0)
#define STAGE_B(t, s) do { \
    gload16(baseB + (long)(t) * 8192,        &lds[(s) * SLOT + 8192 + segoff]); \
    gload16(baseB + (long)(t) * 8192 + 4096, &lds[(s) * SLOT + 8192 + segoff + 4096]); } while (0)

  // fragment read offsets (u16): plane(lane>>4)*2048 + row*8
  const int aoff = (lane >> 4) * 2048 + (wr * 128 + (lane & 15)) * 8;
  const int boff = (lane >> 4) * 2048 + (wc * 64  + (lane & 15)) * 8;

  f32x4_t acc[8][4];
#pragma unroll
  for (int m = 0; m < 8; ++m)
#pragma unroll
    for (int n = 0; n < 4; ++n) acc[m][n] = (f32x4_t){0.f, 0.f, 0.f, 0.f};

  // prologue: stage tiles 0 and 1
  STAGE_A(0, 0); STAGE_B(0, 0);
  STAGE_A(1, 1); STAGE_B(1, 1);
  asm volatile("s_waitcnt vmcnt(4)" ::: "memory");   // tile 0 resident
  __builtin_amdgcn_s_barrier();

  int slot = 0, s2 = 2;
  for (int t = 0; t < NT; ++t) {
    const u16* sA = &lds[slot * SLOT];
    const u16* sB = sA + 8192;
    const bool pre = (t + 2 < NT);

    // issue next-tile staging first (longest latency), then frag reads;
    // compiler interleaves ds_read completion with the MFMA cluster via
    // counted lgkmcnt (no manual drain).
    if (pre) { STAGE_A(t + 2, s2); STAGE_B(t + 2, s2); }

    bf16x8_t bv[4], av[8];
#pragma unroll
    for (int n = 0; n < 4; ++n) bv[n] = *(const bf16x8_t*)&sB[boff + n * 128];
#pragma unroll
    for (int m = 0; m < 8; ++m) av[m] = *(const bf16x8_t*)&sA[aoff + m * 128];

    __builtin_amdgcn_s_setprio(1);
#pragma unroll
    for (int m = 0; m < 8; ++m)
#pragma unroll
      for (int n = 0; n < 4; ++n)
        acc[m][n] = __builtin_amdgcn_mfma_f32_16x16x32_bf16(bv[n], av[m], acc[m][n], 0, 0, 0);
    __builtin_amdgcn_s_setprio(0);

    if (pre) asm volatile("s_waitcnt vmcnt(4)" ::: "memory");  // t+1 resident, t+2 in flight
    else     asm volatile("s_waitcnt vmcnt(0)" ::: "memory");  // epilogue drain
    __builtin_amdgcn_s_barrier();

    slot = (slot == 2) ? 0 : slot + 1;
    s2   = (s2   == 2) ? 0 : s2   + 1;
  }
#undef STAGE_A
#undef STAGE_B

  // epilogue (swapped operands): out row = lane&15, out cols = (lane>>4)*4 + r
  const int rowm = lane & 15;
  const int col4 = (lane >> 4) * 4;
#pragma unroll
  for (int m = 0; m < 8; ++m) {
    long rg = (long)(m0 + wr * 128 + m * 16 + rowm) * NCOL;
#pragma unroll
    for (int n = 0; n < 4; ++n) {
      int cg = n0 + wc * 64 + n * 16 + col4;
      u16x4_t o;
#pragma unroll
      for (int r = 0; r < 4; ++r) o[r] = f2b(acc[m][n][r]);
      *(u16x4_t*)&Cout[rg + cg] = o;
    }
  }
}

// ---------- pass2: gates -> c_new (fp32), A2 packed = [bf16(c_new) | bf16(tanh(c_new))] ----------
__global__ void pass2_kernel(const u16* __restrict__ G1, const float* __restrict__ c_t,
                             const float* __restrict__ bias_i, const float* __restrict__ bias_f,
                             const float* __restrict__ bias_c,
                             float* __restrict__ c_new_out, u16* __restrict__ A2p) {
  int mb = blockIdx.x, jg = blockIdx.y, t = threadIdx.x;
  int b = mb * 256 + t;
  int j0 = jg * 32;
  const u16* row = G1 + (long)b * 8192 + j0;
  const float* cp_p = c_t + (long)b * 2048 + j0;
  float* co_p = c_new_out + (long)b * 2048 + j0;
  u16* dc = A2p + ((long)(mb * 128 + jg)) * 8192 + t * 8;
  u16* dr = dc + (long)64 * 8192;

#pragma unroll
  for (int q = 0; q < 4; ++q) {
    u16x8_t ip = *(const u16x8_t*)(row + q * 8);
    u16x8_t fp = *(const u16x8_t*)(row + 2048 + q * 8);
    u16x8_t gp = *(const u16x8_t*)(row + 4096 + q * 8);
    f32x8_t cp = *(const f32x8_t*)(cp_p + q * 8);
    f32x8_t bi = *(const f32x8_t*)(bias_i + j0 + q * 8);
    f32x8_t bf = *(const f32x8_t*)(bias_f + j0 + q * 8);
    f32x8_t bc = *(const f32x8_t*)(bias_c + j0 + q * 8);
    f32x8_t cn;
    u16x8_t cb, rb;
#pragma unroll
    for (int r = 0; r < 8; ++r) {
      float ig = sigm_(b2f(ip[r]) + bi[r]);
      float fg = sigm_(b2f(fp[r]) + bf[r]);
      float g  = tanh_(b2f(gp[r]) + bc[r]);
      float c  = fg * cp[r] + ig * g;
      cn[r] = c;
      cb[r] = f2b(c);
      rb[r] = f2b(tanh_(c));
    }
    *(f32x8_t*)(co_p + q * 8) = cn;
    *(u16x8_t*)(dc + q * 2048) = cb;
    *(u16x8_t*)(dr + q * 2048) = rb;
  }
}

// ---------- pass3: h_new = sigmoid(og_pre + c@Woc + bias_o) * (m_t + xr) ----------
__global__ void pass3_kernel(const u16* __restrict__ G1, const u16* __restrict__ G2,
                             const float* __restrict__ bias_o, float* __restrict__ h_out) {
  long i = (long)blockIdx.x * blockDim.x + threadIdx.x;
  long e = i * 8;
  int b = (int)(e >> 10);
  int j = (int)(e & 1023);
  const u16* row1 = G1 + (long)b * 8192;
  const u16* row2 = G2 + (long)b * 2048;
  u16x8_t ogp = *(const u16x8_t*)(row1 + 6144 + j);
  u16x8_t xrp = *(const u16x8_t*)(row1 + 7168 + j);
  u16x8_t ocg = *(const u16x8_t*)(row2 + j);
  u16x8_t mt  = *(const u16x8_t*)(row2 + 1024 + j);
  f32x8_t bo  = *(const f32x8_t*)(bias_o + j);
  f32x8_t h;
#pragma unroll
  for (int r = 0; r < 8; ++r) {
    float og = sigm_(b2f(ogp[r]) + b2f(ocg[r]) + bo[r]);
    h[r] = og * (b2f(mt[r]) + b2f(xrp[r]));
  }
  *(f32x8_t*)(h_out + (long)b * 1024 + j) = h;
}

// ---------- launch ----------
extern "C" void kernel_launch(void* const* d_in, const int* in_sizes, int n_in,
                              void* d_out, int out_size, void* d_ws, size_t ws_size,
                              hipStream_t stream) {
  const float* x_t      = (const float*)d_in[0];
  const float* h_t      = (const float*)d_in[1];
  const float* c_t      = (const float*)d_in[2];
  const float* w_if_x   = (const float*)d_in[3];
  const float* w_if_h   = (const float*)d_in[4];
  const float* w_if_c   = (const float*)d_in[5];
  const float* bias_i   = (const float*)d_in[6];
  const float* bias_f   = (const float*)d_in[7];
  const float* w_c_x    = (const float*)d_in[8];
  const float* w_c_h    = (const float*)d_in[9];
  const float* bias_c   = (const float*)d_in[10];
  const float* w_o_x    = (const float*)d_in[11];
  const float* w_o_h    = (const float*)d_in[12];
  const float* w_o_c    = (const float*)d_in[13];
  const float* bias_o   = (const float*)d_in[14];
  const float* w_r_proj = (const float*)d_in[15];
  const float* w_r_x    = (const float*)d_in[16];

  char* ws = (char*)d_ws;
  u16* A1p  = (u16*)(ws);
  u16* W1tp = (u16*)(ws + 167772160L);
  u16* G1   = (u16*)(ws + 251658240L);
  u16* W2tp = (u16*)(ws + 520093696L);
  u16* A2p  = (u16*)(ws);               // aliases A1p (dead after GEMM1)
  u16* G2   = (u16*)(ws + 167772160L);  // aliases W1tp (dead after GEMM1)

  float* h_out = (float*)d_out;
  float* c_out = h_out + 16384L * 1024L;

  // --- stage 0: pack activations (A1 panel k-map: x 0..63, h 64..95, c 96..159) ---
  cvt_act_kernel<<<dim3(64, 64), 256, 0, stream>>>(x_t, A1p, 2048, 160, 0);
  cvt_act_kernel<<<dim3(64, 32), 256, 0, stream>>>(h_t, A1p, 1024, 160, 2048);
  cvt_act_kernel<<<dim3(64, 64), 256, 0, stream>>>(c_t, A1p, 2048, 160, 3072);

  // --- pack weights (transposed) ---
  cvt_wt_kernel<<<dim3(16, 64), 256, 0, stream>>>(w_if_x,   W1tp, 4096, 160, 0,    0);
  cvt_wt_kernel<<<dim3(16, 32), 256, 0, stream>>>(w_if_h,   W1tp, 4096, 160, 0,    2048);
  cvt_wt_kernel<<<dim3(16, 64), 256, 0, stream>>>(w_if_c,   W1tp, 4096, 160, 0,    3072);
  cvt_wt_kernel<<<dim3(8,  64), 256, 0, stream>>>(w_c_x,    W1tp, 2048, 160, 4096, 0);
  cvt_wt_kernel<<<dim3(8,  32), 256, 0, stream>>>(w_c_h,    W1tp, 2048, 160, 4096, 2048);
  cvt_wt_kernel<<<dim3(4,  64), 256, 0, stream>>>(w_o_x,    W1tp, 1024, 160, 6144, 0);
  cvt_wt_kernel<<<dim3(4,  32), 256, 0, stream>>>(w_o_h,    W1tp, 1024, 160, 6144, 2048);
  cvt_wt_kernel<<<dim3(4,  64), 256, 0, stream>>>(w_r_x,    W1tp, 1024, 160, 7168, 0);
  cvt_wt_kernel<<<dim3(4,  64), 256, 0, stream>>>(w_o_c,    W2tp, 1024, 128, 0,    0);
  cvt_wt_kernel<<<dim3(4,  64), 256, 0, stream>>>(w_r_proj, W2tp, 1024, 128, 1024, 2048);

  // --- stage 1: big fused GEMM -> all pre-activations ---
  gemm256_kernel<0><<<2048, 512, 0, stream>>>(A1p, W1tp, G1);

  // --- stage 2: elementwise gates -> c_new + packed A2 ---
  pass2_kernel<<<dim3(64, 64), 256, 0, stream>>>(G1, c_t, bias_i, bias_f, bias_c, c_out, A2p);

  // --- stage 3: [c_new|r_t] GEMM -> og peephole + m_t ---
  gemm256_kernel<1><<<512, 512, 0, stream>>>(A2p, W2tp, G2);

  // --- stage 4: h_new ---
  pass3_kernel<<<8192, 256, 0, stream>>>(G1, G2, bias_o, h_out);
}